// Round 3
// baseline (610.250 us; speedup 1.0000x reference)
//
#include <hip/hip_runtime.h>
#include <cstddef>
#include <cstdint>

constexpr int IMG = 256;
constexpr int NPIX = 65536;
constexpr int PW = 258;                 // padded dim of HWC activation buffers
constexpr size_t PREC = (size_t)PW * PW;

typedef _Float16 h8 __attribute__((ext_vector_type(8)));
typedef float f32x4 __attribute__((ext_vector_type(4)));

// ---------------------------------------------------------------------------
// Zero pad records (rows 0,257; cols 0,257) of a padded-HWC f16 buffer.
// ---------------------------------------------------------------------------
template<int CIN>
__device__ __forceinline__ void zero_pad_rec(int i, _Float16* buf)
{
  constexpr int Q = CIN / 8;
  if (i >= 1028 * Q) return;
  int pr = i / Q, qi = i - pr * Q;
  int rec;
  if (pr < 258) rec = pr;                                   // row 0
  else if (pr < 516) rec = 257 * 258 + (pr - 258);          // row 257
  else { int j = pr - 516; rec = (1 + (j >> 1)) * 258 + ((j & 1) ? 257 : 0); }
  *reinterpret_cast<uint4*>(&buf[(size_t)rec * CIN + qi * 8]) = uint4{0, 0, 0, 0};
}

template<int CIN>
__global__ __launch_bounds__(256) void zeropad_k(_Float16* __restrict__ buf)
{
  zero_pad_rec<CIN>(blockIdx.x * 256 + threadIdx.x, buf);
}

// ---------------------------------------------------------------------------
// fp32 CHW -> padded-HWC f16 (interior), pad-zeroing folded into extra blocks.
// ---------------------------------------------------------------------------
template<int CIN>
__global__ __launch_bounds__(256) void prep_hwc_k(
    const float* __restrict__ in, _Float16* __restrict__ out)
{
  int b = blockIdx.x;
  if (b >= 256) { zero_pad_rec<CIN>((b - 256) * 256 + threadIdx.x, out); return; }
  int pix = b * 256 + threadIdx.x;
  int py = pix >> 8, px = pix & 255;
  size_t rec = ((size_t)(py + 1) * PW + px + 1) * CIN;
#pragma unroll
  for (int c0 = 0; c0 < CIN; c0 += 8) {
    _Float16 t[8];
#pragma unroll
    for (int j = 0; j < 8; ++j)
      t[j] = (_Float16)in[(size_t)(c0 + j) * NPIX + pix];
    *reinterpret_cast<uint4*>(&out[rec + c0]) = *reinterpret_cast<uint4*>(t);
  }
}

// ---------------------------------------------------------------------------
// Weight fragment slicing (hi + optional f16 residual lo):
// dst idx = ((t*KC + c)*NBF + fg)*64 + lane, 8 f16; lane holds B[k][n]:
// n = fg*16 + (l&15), cin = c*32 + (l>>4)*8 + j. Zero-fill n >= nvalid.
// ---------------------------------------------------------------------------
__device__ __forceinline__ void wfrag(
    const float* __restrict__ w, int cin_tot, int cin_off, int KC, int NBF,
    int nvalid, int idx, _Float16* __restrict__ oHi, _Float16* __restrict__ oLo)
{
  int l = idx & 63;
  int r = idx >> 6;
  int fg = r % NBF; r /= NBF;
  int c = r % KC;
  int t = r / KC;
  int n = fg * 16 + (l & 15);
  int cinb = c * 32 + (l >> 4) * 8;
  _Float16 vh[8], vl[8];
#pragma unroll
  for (int j = 0; j < 8; ++j) {
    float x = 0.f;
    if (n < nvalid) x = w[((size_t)n * cin_tot + cin_off + cinb + j) * 9 + t];
    vh[j] = (_Float16)x;
    vl[j] = (_Float16)(x - (float)vh[j]);
  }
  *reinterpret_cast<uint4*>(oHi + (size_t)idx * 8) = *reinterpret_cast<uint4*>(vh);
  if (oLo)
    *reinterpret_cast<uint4*>(oLo + (size_t)idx * 8) = *reinterpret_cast<uint4*>(vl);
}

// One launch per branch preps all conv weight buffers + the dcn B-fragments.
// wB layout: [pass p 0..17][coutfrag f 0..3][lane 0..63][8 f16]
//   lane holds B[k_local][n]: n = f*16 + (l&15); k_local = (l>>4)*8 + j;
//   reduction r = p*32 + k_local = (g*9 + k)*8 + c  with t = p*4+(l>>4),
//   g = t/9, k = t%9, c = j;  value = dw[n,g,c,k].
// ---------------------------------------------------------------------------
__global__ __launch_bounds__(256) void wprep_all_k(
    const float* __restrict__ w0, const float* __restrict__ w1,
    const float* __restrict__ w2, const float* __restrict__ w3,
    const float* __restrict__ wf, int wf_cin_off, const float* __restrict__ dw,
    _Float16* b0h, _Float16* b0l, _Float16* b1h, _Float16* b1l,
    _Float16* b2h, _Float16* b2l, _Float16* b3h, _Float16* b3l,
    _Float16* bfh, _Float16* __restrict__ wB)
{
  int idx = blockIdx.x * 256 + threadIdx.x;
  if (idx < 9216)       wfrag(w0, 128, 0, 4, 4, 64, idx, b0h, b0l);
  else if (idx < 13824) wfrag(w1, 64, 0, 2, 4, 64, idx - 9216, b1h, b1l);
  else if (idx < 18432) wfrag(w2, 64, 0, 2, 4, 64, idx - 13824, b2h, b2l);
  else if (idx < 36864) wfrag(w3, 64, 0, 2, 16, 216, idx - 18432, b3h, b3l);
  else if (idx < 41472) wfrag(wf, 128, wf_cin_off, 2, 4, 64, idx - 36864, bfh, nullptr);
  else if (idx < 46080) {
    int i = idx - 41472;
    int l = i & 63;
    int r = i >> 6;          // 0..71
    int f = r & 3;
    int p = r >> 2;          // 0..17
    int t = p * 4 + (l >> 4);
    int g = (t * 57) >> 9;   // t/9 for t<72
    int k = t - 9 * g;
    int n = f * 16 + (l & 15);
    _Float16 v[8];
#pragma unroll
    for (int j = 0; j < 8; ++j)
      v[j] = (_Float16)dw[(size_t)n * 576 + g * 72 + j * 9 + k];
    *reinterpret_cast<uint4*>(wB + (size_t)i * 8) = *reinterpret_cast<uint4*>(v);
  }
}

// ---------------------------------------------------------------------------
// MFMA implicit-GEMM 3x3 conv over padded-HWC f16.
// DBL: weights hi/lo split (D = Ah*Bh + Ah*Bl); activations single f16.
// Block: 128 thr = 2 waves; 64 px x 64 couts; wave = 64px(mf4) x 32cout(nf2).
// A staged once in LDS (3 rows x 66 recs, 16B-slot rotation); B in registers
// (tap-lookahead global loads, L2-hot). No barriers in the K-loop.
// XCD row-band swizzle: XCD i handles image rows i*32..i*32+31.
// EPI 0: padded-HWC f16 out + bias + lrelu
// EPI 1: OT CHW out + bias (LDS transpose)
// EPI 2: float CHW accumulate (no bias)
// ---------------------------------------------------------------------------
template<int CIN, int EPI, bool DBL, typename OT>
__global__ __launch_bounds__(128) void conv_mfma_k(
    const _Float16* __restrict__ act, const _Float16* __restrict__ wHi,
    const _Float16* __restrict__ wLo, const float* __restrict__ bias,
    OT* __restrict__ out, int ncout, int NBF)
{
  constexpr int Q = CIN / 8;
  constexpr int KC = CIN / 32;
  constexpr int NT = DBL ? 2 : 1;
  constexpr int NREC = 198;            // 3 rows x 66 cols
  __shared__ __align__(16) _Float16 sA[NREC * CIN];

  const int tid = threadIdx.x;
  const int lane = tid & 63;
  const int wv = tid >> 6;
  const int b = blockIdx.x;
  const int inner = b >> 3;
  const int y = (b & 7) * 32 + (inner & 31);   // XCD row band
  const int x0 = (inner >> 5) << 6;
  const int n0 = blockIdx.y << 6;

  // ---- stage A (rows y..y+2 padded, cols x0..x0+65), 16B-slot rotation
  for (int i = tid; i < NREC * Q; i += 128) {
    int rec = i / Q, q = i - rec * Q;
    int seg = rec / 66, xr = rec - seg * 66;
    size_t g = ((size_t)(y + seg) * PW + x0 + xr) * CIN + q * 8;
    int slot = (q + rec) & (Q - 1);
    *reinterpret_cast<uint4*>(&sA[rec * CIN + slot * 8]) =
        *reinterpret_cast<const uint4*>(&act[g]);
  }

  // ---- B register prefetch: wave covers couts n0 + wv*32 .. +31 (2 frags)
  const int fgb = (n0 >> 4) + wv * 2;
  auto bload = [&](int t, int c, int nf, const _Float16* src) {
    return *reinterpret_cast<const h8*>(
        &src[((((size_t)t * KC + c) * NBF + fgb + nf) * 64 + lane) * 8]);
  };
  h8 Bn[KC][2][NT];
#pragma unroll
  for (int c = 0; c < KC; ++c)
#pragma unroll
    for (int nf = 0; nf < 2; ++nf) {
      Bn[c][nf][0] = bload(0, c, nf, wHi);
      if (DBL) Bn[c][nf][1] = bload(0, c, nf, wLo);
    }

  f32x4 acc[4][2];
#pragma unroll
  for (int a = 0; a < 4; ++a)
#pragma unroll
    for (int n = 0; n < 2; ++n) acc[a][n] = f32x4{0.f, 0.f, 0.f, 0.f};
  __syncthreads();

  const int m = lane & 15, kq = lane >> 4;
#pragma unroll 1
  for (int t = 0; t < 9; ++t) {
    h8 Bc[KC][2][NT];
#pragma unroll
    for (int c = 0; c < KC; ++c)
#pragma unroll
      for (int nf = 0; nf < 2; ++nf) {
        Bc[c][nf][0] = Bn[c][nf][0];
        if (DBL) Bc[c][nf][1] = Bn[c][nf][1];
      }
    if (t < 8) {
#pragma unroll
      for (int c = 0; c < KC; ++c)
#pragma unroll
        for (int nf = 0; nf < 2; ++nf) {
          Bn[c][nf][0] = bload(t + 1, c, nf, wHi);
          if (DBL) Bn[c][nf][1] = bload(t + 1, c, nf, wLo);
        }
    }
    const int lrb = (t / 3) * 66 + (t % 3) + m;
#pragma unroll
    for (int c = 0; c < KC; ++c) {
      const int q = c * 4 + kq;
#pragma unroll
      for (int mf = 0; mf < 4; ++mf) {
        int lr = lrb + mf * 16;
        int slot = (q + lr) & (Q - 1);
        h8 ah = *reinterpret_cast<const h8*>(&sA[lr * CIN + slot * 8]);
#pragma unroll
        for (int nf = 0; nf < 2; ++nf) {
          acc[mf][nf] = __builtin_amdgcn_mfma_f32_16x16x32_f16(
              ah, Bc[c][nf][0], acc[mf][nf], 0, 0, 0);
          if (DBL)
            acc[mf][nf] = __builtin_amdgcn_mfma_f32_16x16x32_f16(
                ah, Bc[c][nf][1], acc[mf][nf], 0, 0, 0);
        }
      }
    }
  }

  if (EPI == 0) {
#pragma unroll
    for (int nf = 0; nf < 2; ++nf) {
      const int ch = wv * 32 + nf * 16 + m;
      const float bv = bias[ch];
#pragma unroll
      for (int mf = 0; mf < 4; ++mf)
#pragma unroll
        for (int r = 0; r < 4; ++r) {
          int p = mf * 16 + kq * 4 + r;
          float v = acc[mf][nf][r] + bv;
          v = (v >= 0.f) ? v : 0.1f * v;
          reinterpret_cast<_Float16*>(out)[((size_t)(y + 1) * PW + x0 + p + 1) * 64 + ch] =
              (_Float16)v;
        }
    }
  } else {
    __syncthreads();                   // all waves done reading sA
    float* sF = reinterpret_cast<float*>(sA);   // [64 couts][68] scratch
#pragma unroll
    for (int mf = 0; mf < 4; ++mf)
#pragma unroll
      for (int nf = 0; nf < 2; ++nf) {
        int ml = mf * 16 + kq * 4;               // px 0..63 (4 at a time)
        int nl = wv * 32 + nf * 16 + m;          // cout 0..63
        f32x4 v = acc[mf][nf];
        if (EPI == 1) {
          float bv = (n0 + nl < ncout) ? bias[n0 + nl] : 0.f;
          v[0] += bv; v[1] += bv; v[2] += bv; v[3] += bv;
        }
        *reinterpret_cast<f32x4*>(&sF[nl * 68 + ml]) = v;
      }
    __syncthreads();
    for (int i = tid; i < 1024; i += 128) {
      int row = i >> 4, cx = (i & 15) * 4;
      int gc = n0 + row;
      if (gc < ncout) {
        f32x4 v = *reinterpret_cast<f32x4*>(&sF[row * 68 + cx]);
        size_t ob = (size_t)gc * NPIX + (size_t)y * IMG + x0 + cx;
        if (EPI == 2) {
          float* op = reinterpret_cast<float*>(out) + ob;
          op[0] += v[0]; op[1] += v[1]; op[2] += v[2]; op[3] += v[3];
        } else if (sizeof(OT) == 2) {
          _Float16 t4[4] = {(_Float16)v[0], (_Float16)v[1],
                            (_Float16)v[2], (_Float16)v[3]};
          *reinterpret_cast<uint2*>(reinterpret_cast<_Float16*>(out) + ob) =
              *reinterpret_cast<uint2*>(t4);
        } else {
          *reinterpret_cast<f32x4*>(reinterpret_cast<float*>(out) + ob) = v;
        }
      }
    }
  }
}

// ---------------------------------------------------------------------------
// feat fp32 CHW -> f16 per-group records featG[g][pix][8]
// ---------------------------------------------------------------------------
__global__ __launch_bounds__(256) void featg_k(
    const float* __restrict__ in, _Float16* __restrict__ out)
{
  int pix = blockIdx.x * 256 + threadIdx.x;
#pragma unroll
  for (int g = 0; g < 8; ++g) {
    _Float16 t[8];
#pragma unroll
    for (int c = 0; c < 8; ++c)
      t[c] = (_Float16)in[(size_t)(g * 8 + c) * NPIX + pix];
    *reinterpret_cast<uint4*>(&out[((size_t)g * NPIX + pix) * 8]) =
        *reinterpret_cast<uint4*>(t);
  }
}

// ---------------------------------------------------------------------------
// MDCN sample + MFMA einsum. Wave = 16 px x 64 couts; K (576) split across
// wave pairs: 8 waves/block; wave (pg = wv&3, ph = wv>>2) does passes
// ph*9..ph*9+8 for pixel group pg, f32 accumulators combined via LDS.
// Lane (m = l&15, tq = l>>4) samples pixel m's bilinear vector s[8] for
// (g,tap) combo t = p*4 + tq; s[8] IS the mfma A-fragment (K=32/pass).
// Grid 1024 blocks x 8 waves = 8192 waves = full machine.
// Pipeline: raws 2 passes ahead, gathers 1 ahead; fast exp/rcp tanh/sigmoid;
// f16 bilinear combine. Writes actF (padded-HWC f16, dcn bias folded).
// ---------------------------------------------------------------------------
__global__ __launch_bounds__(512, 8) void mdcn_mfma_k(
    const _Float16* __restrict__ featG, const _Float16* __restrict__ o216,
    const float* __restrict__ flow, const _Float16* __restrict__ wB,
    const float* __restrict__ bias, _Float16* __restrict__ actF)
{
  __shared__ __align__(16) float sRed[4 * 64 * 16];   // 16 KB

  const int tid = threadIdx.x;
  const int lane = tid & 63;
  const int wv = tid >> 6;
  const int pg = wv & 3;                         // pixel group 0..3
  const int ph = wv >> 2;                        // pass half 0..1
  const int b = blockIdx.x;
  const int inner = b >> 3;
  const int row = (b & 7) * 32 + (inner & 31);   // XCD row band
  const int xseg = inner >> 5;                   // 0..3
  const int m = lane & 15;
  const int tq = lane >> 4;                      // tap-slot 0..3
  const int xw = xseg * 64 + pg * 16;            // wave's base column
  const int x = xw + m;
  const int pix = row * 256 + x;
  const int pbase = ph * 9;

  const float fy = flow[NPIX + pix];   // flow[:, ::-1]: y-offset += flow[1]
  const float fx = flow[pix];
  const float rowf = (float)row, xf = (float)x;

  f32x4 acc[4];
#pragma unroll
  for (int f = 0; f < 4; ++f) acc[f] = f32x4{0.f, 0.f, 0.f, 0.f};

  auto rawload = [&](int p, float& a0, float& a1, float& a2) {
    int t = p * 4 + tq;
    int g = (t * 57) >> 9;     // t/9 for t<72
    int k = t - 9 * g;
    a0 = (float)o216[(size_t)(g * 18 + 2 * k) * NPIX + pix];
    a1 = (float)o216[(size_t)(g * 18 + 2 * k + 1) * NPIX + pix];
    a2 = (float)o216[(size_t)(144 + g * 9 + k) * NPIX + pix];
  };

  // params + issue gathers for pass p (weights in f16, fast tanh/sigmoid)
  auto setup = [&](int p, float s0, float s1, float s2,
                   _Float16& h00, _Float16& h01, _Float16& h10, _Float16& h11,
                   h8& A, h8& B, h8& C, h8& D) {
    const int t = p * 4 + tq;
    const int g = (t * 57) >> 9;
    const int k = t - 9 * g;
    const int kd = (k * 11) >> 5;                // k/3
    const int km = k - 3 * kd;                   // k%3
    const float mm = __builtin_amdgcn_rcpf(1.f + __expf(-s2));
    const float e0 = __expf(2.f * s0);
    const float e1 = __expf(2.f * s1);
    const float th0 = 1.f - 2.f * __builtin_amdgcn_rcpf(e0 + 1.f);
    const float th1 = 1.f - 2.f * __builtin_amdgcn_rcpf(e1 + 1.f);
    const float pyf = rowf + (float)(kd - 1) + 10.f * th0 + fy;
    const float pxf = xf + (float)(km - 1) + 10.f * th1 + fx;
    const float y0f = floorf(pyf), x0f = floorf(pxf);
    const float ly = pyf - y0f, lx = pxf - x0f;
    const int y0 = (int)y0f, x0i = (int)x0f;
    const int y1 = y0 + 1, x1 = x0i + 1;
    const bool vy0 = (unsigned)y0 < (unsigned)IMG, vy1 = (unsigned)y1 < (unsigned)IMG;
    const bool vx0 = (unsigned)x0i < (unsigned)IMG, vx1 = (unsigned)x1 < (unsigned)IMG;
    const int y0c = min(max(y0, 0), IMG - 1), y1c = min(max(y1, 0), IMG - 1);
    const int x0c = min(max(x0i, 0), IMG - 1), x1c = min(max(x1, 0), IMG - 1);
    const float oy = 1.f - ly, ox = 1.f - lx;
    const float py0 = oy * mm, py1 = ly * mm;
    const float w00 = (vy0 && vx0) ? py0 * ox : 0.f;
    const float w01 = (vy0 && vx1) ? py0 * lx : 0.f;
    const float w10 = (vy1 && vx0) ? py1 * ox : 0.f;
    const float w11 = (vy1 && vx1) ? py1 * lx : 0.f;
    h00 = (_Float16)w00; h01 = (_Float16)w01;
    h10 = (_Float16)w10; h11 = (_Float16)w11;
    const _Float16* fg = featG + ((size_t)g << 19);   // g * NPIX * 8
    A = *reinterpret_cast<const h8*>(fg + (size_t)(y0c * IMG + x0c) * 8);
    B = *reinterpret_cast<const h8*>(fg + (size_t)(y0c * IMG + x1c) * 8);
    C = *reinterpret_cast<const h8*>(fg + (size_t)(y1c * IMG + x0c) * 8);
    D = *reinterpret_cast<const h8*>(fg + (size_t)(y1c * IMG + x1c) * 8);
  };

  float r0, r1, r2, s0, s1, s2;
  _Float16 h00, h01, h10, h11, v00, v01, v10, v11;
  h8 ga, gb, gc, gd, na, nb, nc, nd;

  rawload(pbase + 0, s0, s1, s2);
  setup(pbase + 0, s0, s1, s2, h00, h01, h10, h11, ga, gb, gc, gd);
  rawload(pbase + 1, r0, r1, r2);

#pragma unroll 1
  for (int i = 0; i < 9; ++i) {
    const int p = pbase + i;
    // pipeline: issue next pass's gathers + raw loads before consuming cur
    if (i < 8) setup(p + 1, r0, r1, r2, v00, v01, v10, v11, na, nb, nc, nd);
    if (i < 7) rawload(p + 2, r0, r1, r2);

    const _Float16* wp = wB + ((size_t)p * 256 + lane) * 8;
    h8 bf0 = *reinterpret_cast<const h8*>(wp);
    h8 bf1 = *reinterpret_cast<const h8*>(wp + 512);
    h8 bf2 = *reinterpret_cast<const h8*>(wp + 1024);
    h8 bf3 = *reinterpret_cast<const h8*>(wp + 1536);

    h8 af;
#pragma unroll
    for (int j = 0; j < 8; ++j)
      af[j] = (_Float16)(ga[j] * h00 + gb[j] * h01 + gc[j] * h10 + gd[j] * h11);

    acc[0] = __builtin_amdgcn_mfma_f32_16x16x32_f16(af, bf0, acc[0], 0, 0, 0);
    acc[1] = __builtin_amdgcn_mfma_f32_16x16x32_f16(af, bf1, acc[1], 0, 0, 0);
    acc[2] = __builtin_amdgcn_mfma_f32_16x16x32_f16(af, bf2, acc[2], 0, 0, 0);
    acc[3] = __builtin_amdgcn_mfma_f32_16x16x32_f16(af, bf3, acc[3], 0, 0, 0);

    ga = na; gb = nb; gc = nc; gd = nd;
    h00 = v00; h01 = v01; h10 = v10; h11 = v11;
  }

  // ---- combine pass halves through LDS (ph=1 writes, ph=0 adds)
  if (ph == 1) {
    float* dst = &sRed[((size_t)(wv - 4) * 64 + lane) * 16];
#pragma unroll
    for (int f = 0; f < 4; ++f)
      *reinterpret_cast<f32x4*>(dst + f * 4) = acc[f];
  }
  __syncthreads();
  if (ph == 1) return;
  const float* src = &sRed[((size_t)wv * 64 + lane) * 16];
#pragma unroll
  for (int f = 0; f < 4; ++f) {
    f32x4 v = *reinterpret_cast<const f32x4*>(src + f * 4);
    acc[f][0] += v[0]; acc[f][1] += v[1]; acc[f][2] += v[2]; acc[f][3] += v[3];
  }

  // epilogue: D[pixel = tq*4+r][cout = f*16+m] -> padded-HWC f16 + bias
  const size_t rb = ((size_t)(row + 1) * PW + xw + 1) * 64;
#pragma unroll
  for (int f = 0; f < 4; ++f) {
    const int ch = f * 16 + m;
    const float bv = bias[ch];
#pragma unroll
    for (int r = 0; r < 4; ++r)
      actF[rb + (size_t)(tq * 4 + r) * 64 + ch] = (_Float16)(acc[f][r] + bv);
  }
}

// ---------------------------------------------------------------------------
extern "C" void kernel_launch(void* const* d_in, const int* in_sizes, int n_in,
                              void* d_out, int out_size, void* d_ws, size_t ws_size,
                              hipStream_t stream)
{
  const float* feat[2]  = {(const float*)d_in[0], (const float*)d_in[1]};
  const float* extra[2] = {(const float*)d_in[2], (const float*)d_in[3]};
  const float* flow[2]  = {(const float*)d_in[4], (const float*)d_in[5]};
  const float* ow[2][4];
  const float* ob[2][4];
  for (int br = 0; br < 2; ++br)
    for (int j = 0; j < 4; ++j) {
      ow[br][j] = (const float*)d_in[6 + br * 8 + j * 2];
      ob[br][j] = (const float*)d_in[6 + br * 8 + j * 2 + 1];
    }
  const float* dcnw[2] = {(const float*)d_in[22], (const float*)d_in[24]};
  const float* dcnb[2] = {(const float*)d_in[23], (const float*)d_in[25]};
  const float* fusw = (const float*)d_in[26];
  const float* fusb = (const float*)d_in[27];

  char* wsb = (char*)d_ws;
  size_t off = 0;
  auto alloc = [&](size_t bytes) {
    void* p = wsb + off;
    off += (bytes + 255) & ~(size_t)255;
    return p;
  };
  // no aliasing: pads of actA/actB/actF survive the whole launch
  _Float16* actI = (_Float16*)alloc(PREC * 128 * 2);
  _Float16* actA = (_Float16*)alloc(PREC * 64 * 2);
  _Float16* actB = (_Float16*)alloc(PREC * 64 * 2);
  _Float16* actF = (_Float16*)alloc(PREC * 64 * 2);
  _Float16* o216 = (_Float16*)alloc((size_t)216 * NPIX * 2);
  _Float16* featG = (_Float16*)alloc((size_t)8 * NPIX * 8 * 2);
  _Float16* wB = (_Float16*)alloc(36864 * 2);
  _Float16* wb0h = (_Float16*)alloc(147456); _Float16* wb0l = (_Float16*)alloc(147456);
  _Float16* wb1h = (_Float16*)alloc(73728);  _Float16* wb1l = (_Float16*)alloc(73728);
  _Float16* wb2h = (_Float16*)alloc(73728);  _Float16* wb2l = (_Float16*)alloc(73728);
  _Float16* wb3h = (_Float16*)alloc(294912); _Float16* wb3l = (_Float16*)alloc(294912);
  _Float16* wbFh = (_Float16*)alloc(73728);
  float* outp = (float*)d_out;

  dim3 blk256(256), blk128(128), blk512(512);
  zeropad_k<64><<<dim3(33), blk256, 0, stream>>>(actA);
  zeropad_k<64><<<dim3(33), blk256, 0, stream>>>(actB);
  zeropad_k<64><<<dim3(33), blk256, 0, stream>>>(actF);

  for (int br = 0; br < 2; ++br) {
    prep_hwc_k<128><<<dim3(321), blk256, 0, stream>>>(extra[br], actI);
    wprep_all_k<<<dim3(180), blk256, 0, stream>>>(
        ow[br][0], ow[br][1], ow[br][2], ow[br][3], fusw, br * 64, dcnw[br],
        wb0h, wb0l, wb1h, wb1l, wb2h, wb2l, wb3h, wb3l, wbFh, wB);

    // offset network (f16 MFMA, hi/lo-split weights)
    conv_mfma_k<128, 0, true, _Float16><<<dim3(1024, 1), blk128, 0, stream>>>(
        actI, wb0h, wb0l, ob[br][0], actA, 64, 4);
    conv_mfma_k<64, 0, true, _Float16><<<dim3(1024, 1), blk128, 0, stream>>>(
        actA, wb1h, wb1l, ob[br][1], actB, 64, 4);
    conv_mfma_k<64, 0, true, _Float16><<<dim3(1024, 1), blk128, 0, stream>>>(
        actB, wb2h, wb2l, ob[br][2], actA, 64, 4);
    conv_mfma_k<64, 1, true, _Float16><<<dim3(1024, 4), blk128, 0, stream>>>(
        actA, wb3h, wb3l, ob[br][3], o216, 216, 16);

    // deformable conv: sample + MFMA einsum, writes actF (bias folded)
    featg_k<<<dim3(256), blk256, 0, stream>>>(feat[br], featG);
    mdcn_mfma_k<<<dim3(1024), blk512, 0, stream>>>(
        featG, o216, flow[br], wB, dcnb[br], actF);

    // fusion conv (single f16)
    if (br == 0)
      conv_mfma_k<64, 1, false, float><<<dim3(1024, 1), blk128, 0, stream>>>(
          actF, wbFh, nullptr, fusb, outp, 64, 4);
    else
      conv_mfma_k<64, 2, false, float><<<dim3(1024, 1), blk128, 0, stream>>>(
          actF, wbFh, nullptr, nullptr, outp, 64, 4);
  }
}

// Round 4
// 515.836 us; speedup vs baseline: 1.1830x; 1.1830x over previous
//
#include <hip/hip_runtime.h>
#include <cstddef>
#include <cstdint>

constexpr int IMG = 256;
constexpr int NPIX = 65536;
constexpr int PW = 258;                 // padded dim of HWC activation buffers
constexpr size_t PREC = (size_t)PW * PW;

typedef _Float16 h8 __attribute__((ext_vector_type(8)));
typedef float f32x4 __attribute__((ext_vector_type(4)));

// ---------------------------------------------------------------------------
// Zero pad records (rows 0,257; cols 0,257) of a padded-HWC f16 buffer.
// ---------------------------------------------------------------------------
template<int CIN>
__device__ __forceinline__ void zero_pad_rec(int i, _Float16* buf)
{
  constexpr int Q = CIN / 8;
  if (i >= 1028 * Q) return;
  int pr = i / Q, qi = i - pr * Q;
  int rec;
  if (pr < 258) rec = pr;                                   // row 0
  else if (pr < 516) rec = 257 * 258 + (pr - 258);          // row 257
  else { int j = pr - 516; rec = (1 + (j >> 1)) * 258 + ((j & 1) ? 257 : 0); }
  *reinterpret_cast<uint4*>(&buf[(size_t)rec * CIN + qi * 8]) = uint4{0, 0, 0, 0};
}

template<int CIN>
__global__ __launch_bounds__(256) void zeropad_k(_Float16* __restrict__ buf)
{
  zero_pad_rec<CIN>(blockIdx.x * 256 + threadIdx.x, buf);
}

// ---------------------------------------------------------------------------
// fp32 CHW -> padded-HWC f16 (interior), pad-zeroing folded into extra blocks.
// ---------------------------------------------------------------------------
template<int CIN>
__global__ __launch_bounds__(256) void prep_hwc_k(
    const float* __restrict__ in, _Float16* __restrict__ out)
{
  int b = blockIdx.x;
  if (b >= 256) { zero_pad_rec<CIN>((b - 256) * 256 + threadIdx.x, out); return; }
  int pix = b * 256 + threadIdx.x;
  int py = pix >> 8, px = pix & 255;
  size_t rec = ((size_t)(py + 1) * PW + px + 1) * CIN;
#pragma unroll
  for (int c0 = 0; c0 < CIN; c0 += 8) {
    _Float16 t[8];
#pragma unroll
    for (int j = 0; j < 8; ++j)
      t[j] = (_Float16)in[(size_t)(c0 + j) * NPIX + pix];
    *reinterpret_cast<uint4*>(&out[rec + c0]) = *reinterpret_cast<uint4*>(t);
  }
}

// ---------------------------------------------------------------------------
// Weight fragment slicing (hi + optional f16 residual lo):
// dst idx = ((t*KC + c)*NBF + fg)*64 + lane, 8 f16; lane holds B[k][n]:
// n = fg*16 + (l&15), cin = c*32 + (l>>4)*8 + j. Zero-fill n >= nvalid.
// ---------------------------------------------------------------------------
__device__ __forceinline__ void wfrag(
    const float* __restrict__ w, int cin_tot, int cin_off, int KC, int NBF,
    int nvalid, int idx, _Float16* __restrict__ oHi, _Float16* __restrict__ oLo)
{
  int l = idx & 63;
  int r = idx >> 6;
  int fg = r % NBF; r /= NBF;
  int c = r % KC;
  int t = r / KC;
  int n = fg * 16 + (l & 15);
  int cinb = c * 32 + (l >> 4) * 8;
  _Float16 vh[8], vl[8];
#pragma unroll
  for (int j = 0; j < 8; ++j) {
    float x = 0.f;
    if (n < nvalid) x = w[((size_t)n * cin_tot + cin_off + cinb + j) * 9 + t];
    vh[j] = (_Float16)x;
    vl[j] = (_Float16)(x - (float)vh[j]);
  }
  *reinterpret_cast<uint4*>(oHi + (size_t)idx * 8) = *reinterpret_cast<uint4*>(vh);
  if (oLo)
    *reinterpret_cast<uint4*>(oLo + (size_t)idx * 8) = *reinterpret_cast<uint4*>(vl);
}

// One launch per branch preps all conv weight buffers + the dcn B-fragments.
// wB layout: [pass p 0..17][coutfrag f 0..3][lane 0..63][8 f16]
//   lane holds B[k_local][n]: n = f*16 + (l&15); k_local = (l>>4)*8 + j;
//   reduction r = p*32 + k_local = (g*9 + k)*8 + c  with t = p*4+(l>>4),
//   g = t/9, k = t%9, c = j;  value = dw[n,g,c,k].
// ---------------------------------------------------------------------------
__global__ __launch_bounds__(256) void wprep_all_k(
    const float* __restrict__ w0, const float* __restrict__ w1,
    const float* __restrict__ w2, const float* __restrict__ w3,
    const float* __restrict__ wf, int wf_cin_off, const float* __restrict__ dw,
    _Float16* b0h, _Float16* b0l, _Float16* b1h, _Float16* b1l,
    _Float16* b2h, _Float16* b2l, _Float16* b3h, _Float16* b3l,
    _Float16* bfh, _Float16* __restrict__ wB)
{
  int idx = blockIdx.x * 256 + threadIdx.x;
  if (idx < 9216)       wfrag(w0, 128, 0, 4, 4, 64, idx, b0h, b0l);
  else if (idx < 13824) wfrag(w1, 64, 0, 2, 4, 64, idx - 9216, b1h, b1l);
  else if (idx < 18432) wfrag(w2, 64, 0, 2, 4, 64, idx - 13824, b2h, b2l);
  else if (idx < 36864) wfrag(w3, 64, 0, 2, 16, 216, idx - 18432, b3h, b3l);
  else if (idx < 41472) wfrag(wf, 128, wf_cin_off, 2, 4, 64, idx - 36864, bfh, nullptr);
  else if (idx < 46080) {
    int i = idx - 41472;
    int l = i & 63;
    int r = i >> 6;          // 0..71
    int f = r & 3;
    int p = r >> 2;          // 0..17
    int t = p * 4 + (l >> 4);
    int g = (t * 57) >> 9;   // t/9 for t<72
    int k = t - 9 * g;
    int n = f * 16 + (l & 15);
    _Float16 v[8];
#pragma unroll
    for (int j = 0; j < 8; ++j)
      v[j] = (_Float16)dw[(size_t)n * 576 + g * 72 + j * 9 + k];
    *reinterpret_cast<uint4*>(wB + (size_t)i * 8) = *reinterpret_cast<uint4*>(v);
  }
}

// ---------------------------------------------------------------------------
// MFMA implicit-GEMM 3x3 conv over padded-HWC f16.
// DBL: weights hi/lo split (D = Ah*Bh + Ah*Bl); activations single f16.
// Block: 256 thr = 4 waves; 64 px x 64 couts; wave = 64px(mf4) x 16cout.
// A staged once in LDS (3 rows x 66 recs, 16B-slot rotation); B in registers
// (tap-lookahead global loads, L2-hot). No barriers in the K-loop.
// XCD row-band swizzle: XCD i handles image rows i*32..i*32+31.
// EPI 0: padded-HWC f16 out + bias + lrelu
// EPI 1: OT CHW out + bias (LDS transpose)
// EPI 2: float CHW accumulate (no bias)
// ---------------------------------------------------------------------------
template<int CIN, int EPI, bool DBL, typename OT>
__global__ __launch_bounds__(256) void conv_mfma_k(
    const _Float16* __restrict__ act, const _Float16* __restrict__ wHi,
    const _Float16* __restrict__ wLo, const float* __restrict__ bias,
    OT* __restrict__ out, int ncout, int NBF)
{
  constexpr int Q = CIN / 8;
  constexpr int KC = CIN / 32;
  constexpr int NT = DBL ? 2 : 1;
  constexpr int NREC = 198;            // 3 rows x 66 cols
  __shared__ __align__(16) _Float16 sA[NREC * CIN];

  const int tid = threadIdx.x;
  const int lane = tid & 63;
  const int wv = tid >> 6;             // 0..3: cout quarter
  const int b = blockIdx.x;
  const int inner = b >> 3;
  const int y = (b & 7) * 32 + (inner & 31);   // XCD row band
  const int x0 = (inner >> 5) << 6;
  const int n0 = blockIdx.y << 6;

  // ---- stage A (rows y..y+2 padded, cols x0..x0+65), 16B-slot rotation
  for (int i = tid; i < NREC * Q; i += 256) {
    int rec = i / Q, q = i - rec * Q;
    int seg = rec / 66, xr = rec - seg * 66;
    size_t g = ((size_t)(y + seg) * PW + x0 + xr) * CIN + q * 8;
    int slot = (q + rec) & (Q - 1);
    *reinterpret_cast<uint4*>(&sA[rec * CIN + slot * 8]) =
        *reinterpret_cast<const uint4*>(&act[g]);
  }

  // ---- B register prefetch: wave covers couts n0 + wv*16 .. +15 (1 frag)
  const int fgb = (n0 >> 4) + wv;
  auto bload = [&](int t, int c, const _Float16* src) {
    return *reinterpret_cast<const h8*>(
        &src[((((size_t)t * KC + c) * NBF + fgb) * 64 + lane) * 8]);
  };
  h8 Bn[KC][NT];
#pragma unroll
  for (int c = 0; c < KC; ++c) {
    Bn[c][0] = bload(0, c, wHi);
    if (DBL) Bn[c][1] = bload(0, c, wLo);
  }

  f32x4 acc[4];
#pragma unroll
  for (int a = 0; a < 4; ++a) acc[a] = f32x4{0.f, 0.f, 0.f, 0.f};
  __syncthreads();

  const int m = lane & 15, kq = lane >> 4;
#pragma unroll 1
  for (int t = 0; t < 9; ++t) {
    h8 Bc[KC][NT];
#pragma unroll
    for (int c = 0; c < KC; ++c) {
      Bc[c][0] = Bn[c][0];
      if (DBL) Bc[c][1] = Bn[c][1];
    }
    if (t < 8) {
#pragma unroll
      for (int c = 0; c < KC; ++c) {
        Bn[c][0] = bload(t + 1, c, wHi);
        if (DBL) Bn[c][1] = bload(t + 1, c, wLo);
      }
    }
    const int lrb = (t / 3) * 66 + (t % 3) + m;
#pragma unroll
    for (int c = 0; c < KC; ++c) {
      const int q = c * 4 + kq;
#pragma unroll
      for (int mf = 0; mf < 4; ++mf) {
        int lr = lrb + mf * 16;
        int slot = (q + lr) & (Q - 1);
        h8 ah = *reinterpret_cast<const h8*>(&sA[lr * CIN + slot * 8]);
        acc[mf] = __builtin_amdgcn_mfma_f32_16x16x32_f16(
            ah, Bc[c][0], acc[mf], 0, 0, 0);
        if (DBL)
          acc[mf] = __builtin_amdgcn_mfma_f32_16x16x32_f16(
              ah, Bc[c][1], acc[mf], 0, 0, 0);
      }
    }
  }

  if (EPI == 0) {
    const int ch = wv * 16 + m;
    const float bv = bias[ch];
#pragma unroll
    for (int mf = 0; mf < 4; ++mf)
#pragma unroll
      for (int r = 0; r < 4; ++r) {
        int p = mf * 16 + kq * 4 + r;
        float v = acc[mf][r] + bv;
        v = (v >= 0.f) ? v : 0.1f * v;
        reinterpret_cast<_Float16*>(out)[((size_t)(y + 1) * PW + x0 + p + 1) * 64 + ch] =
            (_Float16)v;
      }
  } else {
    __syncthreads();                   // all waves done reading sA
    float* sF = reinterpret_cast<float*>(sA);   // [64 couts][68] scratch
    const int nl = wv * 16 + m;                  // cout 0..63
#pragma unroll
    for (int mf = 0; mf < 4; ++mf) {
      int ml = mf * 16 + kq * 4;                 // px 0..63 (4 at a time)
      f32x4 v = acc[mf];
      if (EPI == 1) {
        float bv = (n0 + nl < ncout) ? bias[n0 + nl] : 0.f;
        v[0] += bv; v[1] += bv; v[2] += bv; v[3] += bv;
      }
      *reinterpret_cast<f32x4*>(&sF[nl * 68 + ml]) = v;
    }
    __syncthreads();
    for (int i = tid; i < 1024; i += 256) {
      int row = i >> 4, cx = (i & 15) * 4;
      int gc = n0 + row;
      if (gc < ncout) {
        f32x4 v = *reinterpret_cast<f32x4*>(&sF[row * 68 + cx]);
        size_t ob = (size_t)gc * NPIX + (size_t)y * IMG + x0 + cx;
        if (EPI == 2) {
          float* op = reinterpret_cast<float*>(out) + ob;
          op[0] += v[0]; op[1] += v[1]; op[2] += v[2]; op[3] += v[3];
        } else if (sizeof(OT) == 2) {
          _Float16 t4[4] = {(_Float16)v[0], (_Float16)v[1],
                            (_Float16)v[2], (_Float16)v[3]};
          *reinterpret_cast<uint2*>(reinterpret_cast<_Float16*>(out) + ob) =
              *reinterpret_cast<uint2*>(t4);
        } else {
          *reinterpret_cast<f32x4*>(reinterpret_cast<float*>(out) + ob) = v;
        }
      }
    }
  }
}

// ---------------------------------------------------------------------------
// feat fp32 CHW -> f16 per-group records featG[g][pix][8]
// ---------------------------------------------------------------------------
__global__ __launch_bounds__(256) void featg_k(
    const float* __restrict__ in, _Float16* __restrict__ out)
{
  int pix = blockIdx.x * 256 + threadIdx.x;
#pragma unroll
  for (int g = 0; g < 8; ++g) {
    _Float16 t[8];
#pragma unroll
    for (int c = 0; c < 8; ++c)
      t[c] = (_Float16)in[(size_t)(g * 8 + c) * NPIX + pix];
    *reinterpret_cast<uint4*>(&out[((size_t)g * NPIX + pix) * 8]) =
        *reinterpret_cast<uint4*>(t);
  }
}

// ---------------------------------------------------------------------------
// MDCN sample + MFMA einsum, all 8 groups accumulated in-register.
// Wave = 16 px x 64 couts. Lane (m = l&15, tq = l>>4) samples pixel m's
// bilinear value vector s[8] for (g,tap) combo t = pass*4 + tq; s[8] IS the
// mfma_f32_16x16x32_f16 A-fragment; 18 passes of K=32 cover all 576.
// Unroll-by-2 ping-pong pipeline (sets A/B, no register moves):
//   body(p): setup(p+1)->NXT.g/w, rawload(p+2)->CUR.raw, bfload(p+1)->NXT.bf,
//            then af(CUR) + 4 MFMA with CUR.bf.
// Raws, gathers AND weight frags all 1 pass ahead. Fast exp/rcp tanh/sigmoid;
// f16 bilinear combine. Writes actF (padded-HWC f16, dcn bias folded).
// XCD row-band swizzle on blockIdx.x; 4 independent waves/block.
// ---------------------------------------------------------------------------
struct GS {
  h8 a, b, c, d;                       // gather corners
  _Float16 w00, w01, w10, w11;         // bilinear*mask weights (f16)
  float r0, r1, r2;                    // raw offsets/mask logits
  h8 bf0, bf1, bf2, bf3;               // weight B-fragments
};

__global__ __launch_bounds__(256, 4) void mdcn_mfma_k(
    const _Float16* __restrict__ featG, const _Float16* __restrict__ o216,
    const float* __restrict__ flow, const _Float16* __restrict__ wB,
    const float* __restrict__ bias, _Float16* __restrict__ actF)
{
  const int tid = threadIdx.x;
  const int lane = tid & 63;
  const int wv = tid >> 6;
  const int b = blockIdx.x;
  const int inner = b >> 3;
  const int row = (b & 7) * 32 + (inner & 31);   // XCD row band
  const int xseg = inner >> 5;                   // 0..3
  const int m = lane & 15;
  const int tq = lane >> 4;                      // tap-slot 0..3
  const int xw = xseg * 64 + wv * 16;            // wave's base column
  const int x = xw + m;
  const int pix = row * 256 + x;

  const float fy = flow[NPIX + pix];   // flow[:, ::-1]: y-offset += flow[1]
  const float fx = flow[pix];
  const float rowf = (float)row, xf = (float)x;

  f32x4 acc[4];
#pragma unroll
  for (int f = 0; f < 4; ++f) acc[f] = f32x4{0.f, 0.f, 0.f, 0.f};

  auto rawloadv = [&](int p, float& a0, float& a1, float& a2) {
    int t = p * 4 + tq;
    int g = (t * 57) >> 9;     // t/9 for t<72
    int k = t - 9 * g;
    a0 = (float)o216[(size_t)(g * 18 + 2 * k) * NPIX + pix];
    a1 = (float)o216[(size_t)(g * 18 + 2 * k + 1) * NPIX + pix];
    a2 = (float)o216[(size_t)(144 + g * 9 + k) * NPIX + pix];
  };

  // params + issue gathers for pass p into set o (fast tanh/sigmoid)
  auto setup = [&](int p, float s0, float s1, float s2, GS& o) {
    const int t = p * 4 + tq;
    const int g = (t * 57) >> 9;
    const int k = t - 9 * g;
    const int kd = (k * 11) >> 5;                // k/3
    const int km = k - 3 * kd;                   // k%3
    const float mm = __builtin_amdgcn_rcpf(1.f + __expf(-s2));
    const float e0 = __expf(2.f * s0);
    const float e1 = __expf(2.f * s1);
    const float th0 = 1.f - 2.f * __builtin_amdgcn_rcpf(e0 + 1.f);
    const float th1 = 1.f - 2.f * __builtin_amdgcn_rcpf(e1 + 1.f);
    const float pyf = rowf + (float)(kd - 1) + 10.f * th0 + fy;
    const float pxf = xf + (float)(km - 1) + 10.f * th1 + fx;
    const float y0f = floorf(pyf), x0f = floorf(pxf);
    const float ly = pyf - y0f, lx = pxf - x0f;
    const int y0 = (int)y0f, x0i = (int)x0f;
    const int y1 = y0 + 1, x1 = x0i + 1;
    const bool vy0 = (unsigned)y0 < (unsigned)IMG, vy1 = (unsigned)y1 < (unsigned)IMG;
    const bool vx0 = (unsigned)x0i < (unsigned)IMG, vx1 = (unsigned)x1 < (unsigned)IMG;
    const int y0c = min(max(y0, 0), IMG - 1), y1c = min(max(y1, 0), IMG - 1);
    const int x0c = min(max(x0i, 0), IMG - 1), x1c = min(max(x1, 0), IMG - 1);
    const float oy = 1.f - ly, ox = 1.f - lx;
    const float py0 = oy * mm, py1 = ly * mm;
    const float w00 = (vy0 && vx0) ? py0 * ox : 0.f;
    const float w01 = (vy0 && vx1) ? py0 * lx : 0.f;
    const float w10 = (vy1 && vx0) ? py1 * ox : 0.f;
    const float w11 = (vy1 && vx1) ? py1 * lx : 0.f;
    o.w00 = (_Float16)w00; o.w01 = (_Float16)w01;
    o.w10 = (_Float16)w10; o.w11 = (_Float16)w11;
    const _Float16* fg = featG + ((size_t)g << 19);   // g * NPIX * 8
    o.a = *reinterpret_cast<const h8*>(fg + (size_t)(y0c * IMG + x0c) * 8);
    o.b = *reinterpret_cast<const h8*>(fg + (size_t)(y0c * IMG + x1c) * 8);
    o.c = *reinterpret_cast<const h8*>(fg + (size_t)(y1c * IMG + x0c) * 8);
    o.d = *reinterpret_cast<const h8*>(fg + (size_t)(y1c * IMG + x1c) * 8);
  };

  auto bfload = [&](int p, GS& o) {
    const _Float16* wp = wB + ((size_t)p * 256 + lane) * 8;
    o.bf0 = *reinterpret_cast<const h8*>(wp);
    o.bf1 = *reinterpret_cast<const h8*>(wp + 512);
    o.bf2 = *reinterpret_cast<const h8*>(wp + 1024);
    o.bf3 = *reinterpret_cast<const h8*>(wp + 1536);
  };

  auto consume = [&](GS& cur) {
    h8 af;
#pragma unroll
    for (int j = 0; j < 8; ++j)
      af[j] = (_Float16)(cur.a[j] * cur.w00 + cur.b[j] * cur.w01 +
                         cur.c[j] * cur.w10 + cur.d[j] * cur.w11);
    acc[0] = __builtin_amdgcn_mfma_f32_16x16x32_f16(af, cur.bf0, acc[0], 0, 0, 0);
    acc[1] = __builtin_amdgcn_mfma_f32_16x16x32_f16(af, cur.bf1, acc[1], 0, 0, 0);
    acc[2] = __builtin_amdgcn_mfma_f32_16x16x32_f16(af, cur.bf2, acc[2], 0, 0, 0);
    acc[3] = __builtin_amdgcn_mfma_f32_16x16x32_f16(af, cur.bf3, acc[3], 0, 0, 0);
  };

  auto body = [&](int p, GS& cur, GS& nxt) {
    setup(p + 1, nxt.r0, nxt.r1, nxt.r2, nxt);   // gathers for p+1
    rawloadv(p + 2, cur.r0, cur.r1, cur.r2);     // raws for p+2
    bfload(p + 1, nxt);                          // weight frags for p+1
    consume(cur);
  };

  GS A, B;
  // prologue: fill pass-0 state and pass-1 raws
  {
    float t0, t1, t2;
    rawloadv(0, t0, t1, t2);
    rawloadv(1, B.r0, B.r1, B.r2);
    bfload(0, A);
    setup(0, t0, t1, t2, A);
  }

#pragma unroll 1
  for (int it = 0; it < 8; ++it) {     // bodies p = 0..15 (full pipeline)
    body(2 * it, A, B);
    body(2 * it + 1, B, A);
  }
  // tail: p=16 (no rawload), p=17 (consume only)
  setup(17, B.r0, B.r1, B.r2, B);
  bfload(17, B);
  consume(A);
  consume(B);

  // epilogue: D[pixel = tq*4+r][cout = f*16+m] -> padded-HWC f16 + bias
  const size_t rb = ((size_t)(row + 1) * PW + xw + 1) * 64;
#pragma unroll
  for (int f = 0; f < 4; ++f) {
    const int ch = f * 16 + m;
    const float bv = bias[ch];
#pragma unroll
    for (int r = 0; r < 4; ++r)
      actF[rb + (size_t)(tq * 4 + r) * 64 + ch] = (_Float16)(acc[f][r] + bv);
  }
}

// ---------------------------------------------------------------------------
extern "C" void kernel_launch(void* const* d_in, const int* in_sizes, int n_in,
                              void* d_out, int out_size, void* d_ws, size_t ws_size,
                              hipStream_t stream)
{
  const float* feat[2]  = {(const float*)d_in[0], (const float*)d_in[1]};
  const float* extra[2] = {(const float*)d_in[2], (const float*)d_in[3]};
  const float* flow[2]  = {(const float*)d_in[4], (const float*)d_in[5]};
  const float* ow[2][4];
  const float* ob[2][4];
  for (int br = 0; br < 2; ++br)
    for (int j = 0; j < 4; ++j) {
      ow[br][j] = (const float*)d_in[6 + br * 8 + j * 2];
      ob[br][j] = (const float*)d_in[6 + br * 8 + j * 2 + 1];
    }
  const float* dcnw[2] = {(const float*)d_in[22], (const float*)d_in[24]};
  const float* dcnb[2] = {(const float*)d_in[23], (const float*)d_in[25]};
  const float* fusw = (const float*)d_in[26];
  const float* fusb = (const float*)d_in[27];

  char* wsb = (char*)d_ws;
  size_t off = 0;
  auto alloc = [&](size_t bytes) {
    void* p = wsb + off;
    off += (bytes + 255) & ~(size_t)255;
    return p;
  };
  // no aliasing: pads of actA/actB/actF survive the whole launch
  _Float16* actI = (_Float16*)alloc(PREC * 128 * 2);
  _Float16* actA = (_Float16*)alloc(PREC * 64 * 2);
  _Float16* actB = (_Float16*)alloc(PREC * 64 * 2);
  _Float16* actF = (_Float16*)alloc(PREC * 64 * 2);
  _Float16* o216 = (_Float16*)alloc((size_t)216 * NPIX * 2);
  _Float16* featG = (_Float16*)alloc((size_t)8 * NPIX * 8 * 2);
  _Float16* wB = (_Float16*)alloc(36864 * 2);
  _Float16* wb0h = (_Float16*)alloc(147456); _Float16* wb0l = (_Float16*)alloc(147456);
  _Float16* wb1h = (_Float16*)alloc(73728);  _Float16* wb1l = (_Float16*)alloc(73728);
  _Float16* wb2h = (_Float16*)alloc(73728);  _Float16* wb2l = (_Float16*)alloc(73728);
  _Float16* wb3h = (_Float16*)alloc(294912); _Float16* wb3l = (_Float16*)alloc(294912);
  _Float16* wbFh = (_Float16*)alloc(73728);
  float* outp = (float*)d_out;

  dim3 blk256(256);
  zeropad_k<64><<<dim3(33), blk256, 0, stream>>>(actA);
  zeropad_k<64><<<dim3(33), blk256, 0, stream>>>(actB);
  zeropad_k<64><<<dim3(33), blk256, 0, stream>>>(actF);

  for (int br = 0; br < 2; ++br) {
    prep_hwc_k<128><<<dim3(321), blk256, 0, stream>>>(extra[br], actI);
    wprep_all_k<<<dim3(180), blk256, 0, stream>>>(
        ow[br][0], ow[br][1], ow[br][2], ow[br][3], fusw, br * 64, dcnw[br],
        wb0h, wb0l, wb1h, wb1l, wb2h, wb2l, wb3h, wb3l, wbFh, wB);

    // offset network (f16 MFMA, hi/lo-split weights)
    conv_mfma_k<128, 0, true, _Float16><<<dim3(1024, 1), blk256, 0, stream>>>(
        actI, wb0h, wb0l, ob[br][0], actA, 64, 4);
    conv_mfma_k<64, 0, true, _Float16><<<dim3(1024, 1), blk256, 0, stream>>>(
        actA, wb1h, wb1l, ob[br][1], actB, 64, 4);
    conv_mfma_k<64, 0, true, _Float16><<<dim3(1024, 1), blk256, 0, stream>>>(
        actB, wb2h, wb2l, ob[br][2], actA, 64, 4);
    conv_mfma_k<64, 1, true, _Float16><<<dim3(1024, 4), blk256, 0, stream>>>(
        actA, wb3h, wb3l, ob[br][3], o216, 216, 16);

    // deformable conv: sample + MFMA einsum, writes actF (bias folded)
    featg_k<<<dim3(256), blk256, 0, stream>>>(feat[br], featG);
    mdcn_mfma_k<<<dim3(1024), blk256, 0, stream>>>(
        featG, o216, flow[br], wB, dcnb[br], actF);

    // fusion conv (single f16)
    if (br == 0)
      conv_mfma_k<64, 1, false, float><<<dim3(1024, 1), blk256, 0, stream>>>(
          actF, wbFh, nullptr, fusb, outp, 64, 4);
    else
      conv_mfma_k<64, 2, false, float><<<dim3(1024, 1), blk256, 0, stream>>>(
          actF, wbFh, nullptr, nullptr, outp, 64, 4);
  }
}